// Round 4
// baseline (146.196 us; speedup 1.0000x reference)
//
#include <hip/hip_runtime.h>
#include <hip/hip_bf16.h>

// SE(3)-equivariant layer, MI355X / gfx950 — round 4.
// r3 diagnosis: edge kernel 61µs at 19.5% occupancy (162KB LDS -> 1 blk/CU,
// 8 waves), latency-bound t-loop (64 W2 b128 + ~60 scalar feat reads per
// wave-tile) + serial segment-reduce tail. r4: 16-wave t-split blocks
// (halve W2 reads/wave, 2x occupancy), feats in registers, column-major
// summand for vectorizable reduce, prep absorbs scatter.

typedef __attribute__((ext_vector_type(8))) short bf16x8;
typedef __attribute__((ext_vector_type(8))) unsigned short u16x8;
typedef __attribute__((ext_vector_type(4))) float f32x4;

#define NN 10000
#define NE 160000

__device__ __forceinline__ float sus_f(float t) { return t > 0.0f ? __expf(-1.0f / t) : 0.0f; }
__device__ __forceinline__ unsigned int f2bf(float f) {
    unsigned int u = __float_as_uint(f);
    u += 0x7FFFu + ((u >> 16) & 1u);
    return u >> 16;
}
__device__ __forceinline__ float bf2f(unsigned short v) { return __uint_as_float(((unsigned int)v) << 16); }
__device__ __forceinline__ float bflo(unsigned int v) { return __uint_as_float(v << 16); }
__device__ __forceinline__ float bfhi(unsigned int v) { return __uint_as_float(v & 0xFFFF0000u); }
__device__ __forceinline__ float bfe(u16x8 v, int i) { return __uint_as_float(((unsigned int)v[i]) << 16); }

#define GL16(g, l) __builtin_amdgcn_global_load_lds( \
    (const __attribute__((address_space(1))) void*)(g), \
    (__attribute__((address_space(3))) void*)(l), 16, 0, 0)

__device__ __forceinline__ void stageN(const void* g, void* l, int bytes, int tid, int nthr) {
    const char* gc = (const char*)g;
    char* lc = (char*)l;
    const int units = bytes >> 4;
    for (int u = tid; u < units; u += nthr) GL16(gc + ((long)u << 4), lc + (u << 4));
}

// ---------------- hist + W2->bf16 conversion ----------------
__global__ void hist_k(const int* __restrict__ dst, int* __restrict__ hist,
                       const float* __restrict__ w2, char* __restrict__ w2bf) {
    if (blockIdx.x < 625) {
        const int e = blockIdx.x * 256 + threadIdx.x;
        if (e < NE) atomicAdd(&hist[dst[e]], 1);
    } else {
        // W2 -> bf16, transposed + swizzled: row R (out col), chunk j holds k=8j..8j+7
        const int idx = (blockIdx.x - 625) * 256 + threadIdx.x;  // 0..8191
        const int j = idx >> 10, R = idx & 1023;
        unsigned int pk[4];
        #pragma unroll
        for (int p = 0; p < 4; ++p) {
            const unsigned int lo = f2bf(w2[(size_t)(8 * j + 2 * p) * 1024 + R]);
            const unsigned int hi = f2bf(w2[(size_t)(8 * j + 2 * p + 1) * 1024 + R]);
            pk[p] = lo | (hi << 16);
        }
        uint4 v; v.x = pk[0]; v.y = pk[1]; v.z = pk[2]; v.w = pk[3];
        *(uint4*)(w2bf + R * 128 + ((j ^ (R & 7)) << 4)) = v;
    }
}

__global__ __launch_bounds__(1024) void scan_k(const int* __restrict__ hist,
                                               int* __restrict__ offsets) {
    __shared__ int hl[NN];
    __shared__ int wsum[16];
    const int tid = threadIdx.x;
    for (int i = tid; i < NN; i += 1024) hl[i] = hist[i];
    __syncthreads();
    const int base = tid * 10;
    int loc[10]; int s = 0;
    #pragma unroll
    for (int i = 0; i < 10; ++i) { loc[i] = s; const int b = base + i; s += (b < NN) ? hl[b] : 0; }
    int v = s;
    const int lane = tid & 63, wv = tid >> 6;
    #pragma unroll
    for (int d = 1; d < 64; d <<= 1) { int t2 = __shfl_up(v, d); if (lane >= d) v += t2; }
    if (lane == 63) wsum[wv] = v;
    __syncthreads();
    if (tid < 64) {
        int w = (tid < 16) ? wsum[tid] : 0;
        #pragma unroll
        for (int d = 1; d < 16; d <<= 1) { int t2 = __shfl_up(w, d); if (tid >= d) w += t2; }
        if (tid < 16) wsum[tid] = w;
    }
    __syncthreads();
    const int wexc = (wv == 0) ? 0 : wsum[wv - 1];
    const int texc = wexc + v - s;
    #pragma unroll
    for (int i = 0; i < 10; ++i) { const int b = base + i; if (b < NN) offsets[b] = texc + loc[i]; }
    if (tid == 1023) offsets[NN] = texc + s;
}

// ---------------- prep: scatter + radial + MLP + gather, per ORIGINAL edge ----------------
__global__ __launch_bounds__(256, 4) void prep_k(
    const float* __restrict__ x, const float* __restrict__ edge_vec,
    const float* __restrict__ w1, const int* __restrict__ src,
    const int* __restrict__ dst, const int* __restrict__ offsets,
    int* __restrict__ cursor, int* __restrict__ dsts,
    char* __restrict__ h_bf, char* __restrict__ X0g, char* __restrict__ Zg,
    char* __restrict__ X1g, float* __restrict__ Y1g)
{
    __shared__ float embl[128][10];
    __shared__ float y1l[128][4];
    __shared__ int srcl[128];
    __shared__ int posl[128];
    __shared__ float w1l[640];
    const int tid = threadIdx.x;
    const int e0 = blockIdx.x * 128;

    for (int i = tid; i < 640; i += 256) w1l[i] = w1[i];
    if (tid < 128) {
        const int eid = e0 + tid;
        const int d = dst[eid];
        const int pos = offsets[d] + atomicAdd(&cursor[d], 1);
        posl[tid] = pos;
        dsts[pos] = d;
        const float vx = edge_vec[eid * 3 + 0];
        const float vy = edge_vec[eid * 3 + 1];
        const float vz = edge_vec[eid * 3 + 2];
        const float r = sqrtf(vx * vx + vy * vy + vz * vz);
        const float sc = 1.7320508075688772f / r;
        y1l[tid][0] = vx * sc; y1l[tid][1] = vy * sc; y1l[tid][2] = vz * sc; y1l[tid][3] = 0.f;
        *(float4*)&Y1g[(size_t)pos * 4] = make_float4(vx * sc, vy * sc, vz * sc, 0.f);
        srcl[tid] = src[eid];
        const float C0 = 1.14136f * __expf(2.0f) * 3.1622776601683795f; // * sqrt(10)
        #pragma unroll
        for (int i = 0; i < 10; ++i) {
            const float diff = r * (11.0f / 4.5f) - (float)(i + 1);
            embl[tid][i] = C0 * sus_f(diff + 1.0f) * sus_f(1.0f - diff);
        }
    }
    __syncthreads();
    // h = sqrt(2/10)*relu(emb@W1) -> bf16, swizzled slot j^(pos&7)
    for (int idx = tid; idx < 1024; idx += 256) {
        const int e = idx >> 3, j = idx & 7;
        float acc[8];
        #pragma unroll
        for (int jj = 0; jj < 8; ++jj) acc[jj] = 0.0f;
        #pragma unroll
        for (int i = 0; i < 10; ++i) {
            const float ei = embl[e][i];
            #pragma unroll
            for (int jj = 0; jj < 8; ++jj) acc[jj] += ei * w1l[i * 64 + j * 8 + jj];
        }
        unsigned int pk[4];
        #pragma unroll
        for (int p = 0; p < 4; ++p) {
            const unsigned int lo = f2bf(fmaxf(acc[2 * p],     0.0f) * 0.4472135954999579f);
            const unsigned int hi = f2bf(fmaxf(acc[2 * p + 1], 0.0f) * 0.4472135954999579f);
            pk[p] = lo | (hi << 16);
        }
        const int pos = posl[e];
        uint4 v; v.x = pk[0]; v.y = pk[1]; v.z = pk[2]; v.w = pk[3];
        *(uint4*)(h_bf + (size_t)pos * 128 + ((j ^ (pos & 7)) << 4)) = v;
    }
    // X0 bf16 [16] -> 32B rows
    for (int idx = tid; idx < 1024; idx += 256) {
        const int e = idx >> 3, p = idx & 7;
        const int s = srcl[e];
        const float2 ab = *(const float2*)&x[(size_t)s * 64 + 2 * p];
        *(unsigned int*)(X0g + (size_t)posl[e] * 32 + p * 4) = f2bf(ab.x) | (f2bf(ab.y) << 16);
    }
    // Z bf16 [16] -> 32B rows: z[u] = x1[u].y1
    for (int idx = tid; idx < 1024; idx += 256) {
        const int e = idx >> 3, p = idx & 7;
        const int s = srcl[e];
        const float* xp = x + (size_t)s * 64 + 16 + 6 * p;
        const float z0 = xp[0] * y1l[e][0] + xp[1] * y1l[e][1] + xp[2] * y1l[e][2];
        const float z1 = xp[3] * y1l[e][0] + xp[4] * y1l[e][1] + xp[5] * y1l[e][2];
        *(unsigned int*)(Zg + (size_t)posl[e] * 32 + p * 4) = f2bf(z0) | (f2bf(z1) << 16);
    }
    // X1 bf16 padded [16][4] -> 128B rows (8B aligned per u for b64 reads)
    for (int idx = tid; idx < 2048; idx += 256) {
        const int e = idx >> 4, u = idx & 15;
        const int s = srcl[e];
        const float* xp = x + (size_t)s * 64 + 16 + 3 * u;
        uint2 v;
        v.x = f2bf(xp[0]) | (f2bf(xp[1]) << 16);
        v.y = f2bf(xp[2]);
        *(uint2*)(X1g + (size_t)posl[e] * 128 + u * 8) = v;
    }
}

// ---------------- fused edge kernel (paired paths, 16 waves, t-split) ----------------
// buf layout (bytes): hl [128][128] @0 | X0 [128][32] @16384 | Z [128][32] @20480
//                     X1 [128][16][8] @24576 | Y1 [128][16] @40960 | dst [128][4] @43008
#define BUF 43520

__global__ __launch_bounds__(1024, 4) void se3_edge3(
    const char* __restrict__ w2bf, const char* __restrict__ h_bf,
    const char* __restrict__ X0g, const char* __restrict__ Zg,
    const char* __restrict__ X1g, const float* __restrict__ Y1g,
    const int* __restrict__ dsts, float* __restrict__ out)
{
    __shared__ __align__(16) char w2lds[65536];
    __shared__ __align__(16) char bufs[2][BUF];
    __shared__ int segst[2][66];
    __shared__ int nseg[2];

    const int tid = threadIdx.x, lane = tid & 63, wv = tid >> 6;
    const int lm = lane & 15, q = lane >> 4;
    const int g = wv & 7, th = wv >> 3;
    const int erow = g << 4;
    const int bx = blockIdx.x;
    const int pair = bx & 1;
    const int tb = bx >> 1;              // 0..249
    const int s0 = (q ^ (lm & 7)) << 4;
    const int s1 = s0 ^ 64;

    const char* w2p0 = w2lds;
    const char* w2p1 = w2lds + 32768;

    auto stage_tile = [&](char* nb, long e0) {
        stageN(h_bf + e0 * 128, nb, 16384, tid, 1024);
        stageN(X0g + e0 * 32, nb + 16384, 4096, tid, 1024);
        if (pair) {
            stageN(X1g + e0 * 128, nb + 24576, 16384, tid, 1024);
            stageN((const char*)(Y1g + e0 * 4), nb + 40960, 2048, tid, 1024);
        } else {
            stageN(Zg + e0 * 32, nb + 20480, 4096, tid, 1024);
        }
        stageN((const char*)(dsts + e0), nb + 43008, 512, tid, 1024);
    };

    {
        const int pa = pair ? 1 : 0, pb = pair ? 2 : 3;
        stageN(w2bf + pa * 32768, w2lds, 32768, tid, 1024);
        stageN(w2bf + pb * 32768, w2lds + 32768, 32768, tid, 1024);
        stage_tile(bufs[0], (long)tb * 5 * 128);
    }
    __syncthreads();

    const float S = 0.17677669529663687f * 0.125f * 0.0625f; // c * (1/8) * (N/E)

    for (int tt = 0; tt < 5; ++tt) {
        char* buf = bufs[tt & 1];
        const long e0 = ((long)tb * 5 + tt) * 128;
        if (tt < 4) stage_tile(bufs[(tt & 1) ^ 1], e0 + 128);

        // A fragments + register feats
        const int arow = erow + lm;
        const bf16x8 a0 = *(const bf16x8*)(buf + arow * 128 + s0);
        const bf16x8 a1 = *(const bf16x8*)(buf + arow * 128 + s1);
        u16x8 x0r[4], zr[4];
        #pragma unroll
        for (int r = 0; r < 4; ++r) {
            const int el = erow + 4 * q + r;
            x0r[r] = *(const u16x8*)(buf + 16384 + el * 32 + th * 16);
            if (pair == 0) zr[r] = *(const u16x8*)(buf + 20480 + el * 32 + th * 16);
        }

        float ac0[4] = {0,0,0,0}, ac1[4] = {0,0,0,0}, ac2[4] = {0,0,0,0}, ac3[4] = {0,0,0,0};
        #pragma unroll
        for (int tl = 0; tl < 8; ++tl) {
            const int t = (th << 3) + tl;
            const int rowb = (t * 16 + lm) << 7;
            const bf16x8 b00 = *(const bf16x8*)(w2p0 + rowb + s0);
            const bf16x8 b01 = *(const bf16x8*)(w2p0 + rowb + s1);
            const bf16x8 b10 = *(const bf16x8*)(w2p1 + rowb + s0);
            const bf16x8 b11 = *(const bf16x8*)(w2p1 + rowb + s1);
            f32x4 w0 = {0.f,0.f,0.f,0.f}, w1v = {0.f,0.f,0.f,0.f};
            w0 = __builtin_amdgcn_mfma_f32_16x16x32_bf16(a0, b00, w0, 0,0,0);
            w0 = __builtin_amdgcn_mfma_f32_16x16x32_bf16(a1, b01, w0, 0,0,0);
            w1v = __builtin_amdgcn_mfma_f32_16x16x32_bf16(a0, b10, w1v, 0,0,0);
            w1v = __builtin_amdgcn_mfma_f32_16x16x32_bf16(a1, b11, w1v, 0,0,0);
            if (pair == 0) {
                #pragma unroll
                for (int r = 0; r < 4; ++r) {
                    ac0[r] += w0[r] * bfe(x0r[r], tl);
                    ac1[r] += w1v[r] * bfe(zr[r], tl);
                }
            } else {
                #pragma unroll
                for (int r = 0; r < 4; ++r) {
                    const int el = erow + 4 * q + r;
                    const uint2 xv = *(const uint2*)(buf + 24576 + (el * 16 + t) * 8);
                    ac0[r] += w0[r] * bfe(x0r[r], tl);
                    ac1[r] += w1v[r] * bflo(xv.x);
                    ac2[r] += w1v[r] * bfhi(xv.x);
                    ac3[r] += w1v[r] * bflo(xv.y);
                }
            }
        }
        __syncthreads();  // B1: t-loop done (a-frags/feats consumed) -> hl usable as scratch

        if (th == 1) {    // write partials into dead hl region
            char* pb = buf + (g * 64 + lane) * 32;
            if (pair == 0) {
                *(float4*)pb = make_float4(ac0[0], ac0[1], ac0[2], ac0[3]);
                *(float4*)(pb + 16) = make_float4(ac1[0], ac1[1], ac1[2], ac1[3]);
            } else {
                uint4 v0, v1;
                v0.x = f2bf(ac0[0]) | (f2bf(ac0[1]) << 16);
                v0.y = f2bf(ac0[2]) | (f2bf(ac0[3]) << 16);
                v0.z = f2bf(ac1[0]) | (f2bf(ac1[1]) << 16);
                v0.w = f2bf(ac1[2]) | (f2bf(ac1[3]) << 16);
                v1.x = f2bf(ac2[0]) | (f2bf(ac2[1]) << 16);
                v1.y = f2bf(ac2[2]) | (f2bf(ac2[3]) << 16);
                v1.z = f2bf(ac3[0]) | (f2bf(ac3[1]) << 16);
                v1.w = f2bf(ac3[2]) | (f2bf(ac3[3]) << 16);
                *(uint4*)pb = v0;
                *(uint4*)(pb + 16) = v1;
            }
        }
        __syncthreads();  // B2: partials visible

        if (th == 0) {    // merge partials + epilogue into column-major summand
            const char* pb = buf + (g * 64 + lane) * 32;
            if (pair == 0) {
                const float4 p0 = *(const float4*)pb;
                const float4 p1 = *(const float4*)(pb + 16);
                float* sm = (float*)(buf + 16384);
                #pragma unroll
                for (int r = 0; r < 4; ++r) {
                    const int el = erow + 4 * q + r;
                    const float a = ac0[r] + ((const float*)&p0)[r];
                    const float d = ac1[r] + ((const float*)&p1)[r];
                    sm[lm * 129 + el] = S * (a + 0.5773502691896258f * d);
                }
            } else {
                const uint4 v0 = *(const uint4*)pb;
                const uint4 v1 = *(const uint4*)(pb + 16);
                const float pB[4]  = { bflo(v0.x), bfhi(v0.x), bflo(v0.y), bfhi(v0.y) };
                const float pC0[4] = { bflo(v0.z), bfhi(v0.z), bflo(v0.w), bfhi(v0.w) };
                const float pC1[4] = { bflo(v1.x), bfhi(v1.x), bflo(v1.y), bfhi(v1.y) };
                const float pC2[4] = { bflo(v1.z), bfhi(v1.z), bflo(v1.w), bfhi(v1.w) };
                unsigned short* sm = (unsigned short*)(buf + 16384);
                #pragma unroll
                for (int r = 0; r < 4; ++r) {
                    const int el = erow + 4 * q + r;
                    const float4 y = *(const float4*)(buf + 40960 + el * 16);
                    const float b  = S * (ac0[r] + pB[r]);
                    const float c0 = S * (ac1[r] + pC0[r]);
                    const float c1 = S * (ac2[r] + pC1[r]);
                    const float c2 = S * (ac3[r] + pC2[r]);
                    sm[(3 * lm + 0) * 130 + el] = (unsigned short)f2bf(b * y.x + c0);
                    sm[(3 * lm + 1) * 130 + el] = (unsigned short)f2bf(b * y.y + c1);
                    sm[(3 * lm + 2) * 130 + el] = (unsigned short)f2bf(b * y.z + c2);
                }
            }
        }
        const int* dstl = (const int*)(buf + 43008);
        if (wv < 2) {  // segment boundaries per 64-edge half
            const int base = wv << 6;
            const int d = dstl[base + lane];
            const bool flag = (lane == 0) || (d != dstl[base + lane - 1]);
            const unsigned long long m = __ballot(flag);
            const int sid = (lane == 0) ? 0 : __popcll(m & ((1ull << lane) - 1ull));
            if (flag) segst[wv][sid] = base + lane;
            if (lane == 63) { const int ns = __popcll(m); nseg[wv] = ns; segst[wv][ns] = base + 64; }
        }
        __syncthreads();  // B3: summand + segments ready

        const int nsa = nseg[0], nsb = nseg[1];
        if (pair == 0) {
            const float* sm = (const float*)(buf + 16384);
            const int total = (nsa + nsb) << 4;
            for (int i = tid; i < total; i += 1024) {
                const int sg = i >> 4, c = i & 15;
                const int hh = (sg >= nsa) ? 1 : 0;
                const int sl = hh ? sg - nsa : sg;
                const int eb = segst[hh][sl], ee = segst[hh][sl + 1];
                float s = 0.f;
                for (int e = eb; e < ee; ++e) s += sm[c * 129 + e];
                atomicAdd(&out[(size_t)dstl[eb] * 64 + c], s);
            }
        } else {
            const unsigned short* sm = (const unsigned short*)(buf + 16384);
            const int total = (nsa + nsb) * 48;
            for (int i = tid; i < total; i += 1024) {
                const int sg = i / 48, c = i - sg * 48;
                const int hh = (sg >= nsa) ? 1 : 0;
                const int sl = hh ? sg - nsa : sg;
                const int eb = segst[hh][sl], ee = segst[hh][sl + 1];
                float s = 0.f;
                for (int e = eb; e < ee; ++e) s += bf2f(sm[c * 130 + e]);
                atomicAdd(&out[(size_t)dstl[eb] * 64 + 16 + c], s);
            }
        }
        __syncthreads();  // B4: reduce done (buf's summand free for re-staging)
    }
}

// ---------------- fallback (round-2 path, small-ws) ----------------
__global__ void scatter_k(const int* __restrict__ dst, const int* __restrict__ offsets,
                          int* __restrict__ cursor, int* __restrict__ perm,
                          int* __restrict__ dsts) {
    const int e = blockIdx.x * 256 + threadIdx.x;
    if (e < NE) {
        const int d = dst[e];
        const int pos = offsets[d] + atomicAdd(&cursor[d], 1);
        perm[pos] = e;
        dsts[pos] = d;
    }
}

#define FBT 64
template<int PATH>
__device__ __forceinline__ void fb_body(
    const float* __restrict__ x, const float* __restrict__ edge_vec,
    const float* __restrict__ w1, const float* __restrict__ w2,
    const int* __restrict__ src, const int* __restrict__ perm,
    const int* __restrict__ dsts, float* __restrict__ out,
    unsigned short (*w2t)[72], float* arena, float (*y1l)[4],
    int* dstl, int* srcl, int* segstart, int* nseg_s)
{
    constexpr int NC    = (PATH == 0 || PATH == 3) ? 16 : 48;
    constexpr int CBASE = (PATH == 0 || PATH == 3) ? 0 : 16;
    const int tid = threadIdx.x;
    float* embl = arena;
    unsigned short* hl = (unsigned short*)(arena + 640);
    float* feats = arena + 2944;
    float* summ  = arena;
    {
        const float* col = w2 + PATH * 256 + tid;
        #pragma unroll
        for (int k = 0; k < 64; k += 2) {
            const unsigned int lo = f2bf(col[(size_t)k * 1024]);
            const unsigned int hi = f2bf(col[(size_t)(k + 1) * 1024]);
            *(unsigned int*)&w2t[tid][k] = lo | (hi << 16);
        }
    }
    const int lane = tid & 63, wv = tid >> 6, lm = lane & 15, q = lane >> 4;
    const int erow = wv * 16;
    const float C0 = 1.14136f * __expf(2.0f) * 3.1622776601683795f;
    const float S  = 0.17677669529663687f * 0.125f * 0.0625f;
    for (int it = 0; it < 2; ++it) {
        const int e0 = (blockIdx.x * 2 + it) * FBT;
        __syncthreads();
        for (int idx = tid; idx < FBT * 10; idx += 256) {
            const int e = idx / 10, i = idx - e * 10;
            const int eid = perm[e0 + e];
            const float vx = edge_vec[eid * 3 + 0], vy = edge_vec[eid * 3 + 1], vz = edge_vec[eid * 3 + 2];
            const float r = sqrtf(vx * vx + vy * vy + vz * vz);
            const float diff = r * (11.0f / 4.5f) - (float)(i + 1);
            embl[e * 10 + i] = C0 * sus_f(diff + 1.0f) * sus_f(1.0f - diff);
            if (i == 0) {
                const float sc = 1.7320508075688772f / r;
                y1l[e][0] = vx * sc; y1l[e][1] = vy * sc; y1l[e][2] = vz * sc;
                dstl[e] = dsts[e0 + e];
                srcl[e] = src[eid];
            }
        }
        __syncthreads();
        for (int idx = tid; idx < FBT * 8; idx += 256) {
            const int e = idx >> 3, j0 = (idx & 7) * 8;
            float acc[8];
            #pragma unroll
            for (int j = 0; j < 8; ++j) acc[j] = 0.0f;
            #pragma unroll
            for (int i = 0; i < 10; ++i) {
                const float ei = embl[e * 10 + i];
                #pragma unroll
                for (int j = 0; j < 8; ++j) acc[j] += ei * w1[i * 64 + j0 + j];
            }
            unsigned int pk[4];
            #pragma unroll
            for (int p = 0; p < 4; ++p) {
                const unsigned int lo = f2bf(fmaxf(acc[2 * p],     0.0f) * 0.4472135954999579f);
                const unsigned int hi = f2bf(fmaxf(acc[2 * p + 1], 0.0f) * 0.4472135954999579f);
                pk[p] = lo | (hi << 16);
            }
            uint4 v; v.x = pk[0]; v.y = pk[1]; v.z = pk[2]; v.w = pk[3];
            *(uint4*)&hl[e * 72 + j0] = v;
        }
        if (PATH == 2) {
            for (int idx = tid; idx < FBT * 48; idx += 256) {
                const int e = idx / 48, c = idx - e * 48;
                feats[e * 48 + c] = x[(size_t)srcl[e] * 64 + 16 + c];
            }
        } else if (PATH == 3) {
            for (int idx = tid; idx < FBT * 16; idx += 256) {
                const int e = idx >> 4, u = idx & 15;
                const float* xs = x + (size_t)srcl[e] * 64 + 16 + u * 3;
                feats[e * 16 + u] = xs[0] * y1l[e][0] + xs[1] * y1l[e][1] + xs[2] * y1l[e][2];
            }
        } else {
            for (int idx = tid; idx < FBT * 16; idx += 256) {
                const int e = idx >> 4, u = idx & 15;
                feats[e * 16 + u] = x[(size_t)srcl[e] * 64 + u];
            }
        }
        __syncthreads();
        const bf16x8 a0 = *(const bf16x8*)&hl[(erow + lm) * 72 + 8 * q];
        const bf16x8 a1 = *(const bf16x8*)&hl[(erow + lm) * 72 + 32 + 8 * q];
        float accO[4] = {0.f,0.f,0.f,0.f}, accC0[4] = {0.f,0.f,0.f,0.f};
        float accC1[4] = {0.f,0.f,0.f,0.f}, accC2[4] = {0.f,0.f,0.f,0.f};
        #pragma unroll 4
        for (int t = 0; t < 16; ++t) {
            const bf16x8 b0 = *(const bf16x8*)&w2t[t * 16 + lm][8 * q];
            const bf16x8 b1 = *(const bf16x8*)&w2t[t * 16 + lm][32 + 8 * q];
            f32x4 wa = {0.f,0.f,0.f,0.f};
            wa = __builtin_amdgcn_mfma_f32_16x16x32_bf16(a0, b0, wa, 0, 0, 0);
            wa = __builtin_amdgcn_mfma_f32_16x16x32_bf16(a1, b1, wa, 0, 0, 0);
            #pragma unroll
            for (int r = 0; r < 4; ++r) {
                const int el = erow + 4 * q + r;
                if (PATH == 2) {
                    accC0[r] += wa[r] * feats[el * 48 + t * 3 + 0];
                    accC1[r] += wa[r] * feats[el * 48 + t * 3 + 1];
                    accC2[r] += wa[r] * feats[el * 48 + t * 3 + 2];
                } else {
                    accO[r] += wa[r] * feats[el * 16 + t];
                }
            }
        }
        __syncthreads();
        #pragma unroll
        for (int r = 0; r < 4; ++r) {
            const int el = erow + 4 * q + r;
            if (PATH == 0) summ[el * 16 + lm] = S * accO[r];
            else if (PATH == 3) summ[el * 16 + lm] = S * 0.5773502691896258f * accO[r];
            else if (PATH == 1) {
                const float tv = S * accO[r];
                summ[el * 48 + lm * 3 + 0] = tv * y1l[el][0];
                summ[el * 48 + lm * 3 + 1] = tv * y1l[el][1];
                summ[el * 48 + lm * 3 + 2] = tv * y1l[el][2];
            } else {
                summ[el * 48 + lm * 3 + 0] = S * accC0[r];
                summ[el * 48 + lm * 3 + 1] = S * accC1[r];
                summ[el * 48 + lm * 3 + 2] = S * accC2[r];
            }
        }
        if (tid < 64) {
            const int d = dstl[tid];
            const bool flag = (tid == 0) || (d != dstl[tid - 1]);
            const unsigned long long m = __ballot(flag);
            const int sid = (tid == 0) ? 0 : __popcll(m & ((1ull << tid) - 1ull));
            if (flag) segstart[sid] = tid;
            if (tid == 63) { const int ns = __popcll(m); *nseg_s = ns; segstart[ns] = 64; }
        }
        __syncthreads();
        const int ns = *nseg_s;
        for (int i = tid; i < ns * NC; i += 256) {
            const int s = i / NC, c = i - s * NC;
            const int eb = segstart[s], ee = segstart[s + 1];
            float sum = 0.0f;
            for (int e = eb; e < ee; ++e) sum += summ[e * NC + c];
            atomicAdd(&out[(size_t)dstl[eb] * 64 + CBASE + c], sum);
        }
    }
}

__global__ __launch_bounds__(256, 2) void fb_edge(
    const float* __restrict__ x, const float* __restrict__ edge_vec,
    const float* __restrict__ w1, const float* __restrict__ w2,
    const int* __restrict__ src, const int* __restrict__ perm,
    const int* __restrict__ dsts, float* __restrict__ out)
{
    __shared__ unsigned short w2t[256][72];
    __shared__ float arena[6016];
    __shared__ float y1l[FBT][4];
    __shared__ int dstl[FBT];
    __shared__ int srcl[FBT];
    __shared__ int segstart[FBT + 1];
    __shared__ int nseg_s;
    switch (blockIdx.y) {
        case 0:  fb_body<0>(x, edge_vec, w1, w2, src, perm, dsts, out, w2t, arena, y1l, dstl, srcl, segstart, &nseg_s); break;
        case 1:  fb_body<1>(x, edge_vec, w1, w2, src, perm, dsts, out, w2t, arena, y1l, dstl, srcl, segstart, &nseg_s); break;
        case 2:  fb_body<2>(x, edge_vec, w1, w2, src, perm, dsts, out, w2t, arena, y1l, dstl, srcl, segstart, &nseg_s); break;
        default: fb_body<3>(x, edge_vec, w1, w2, src, perm, dsts, out, w2t, arena, y1l, dstl, srcl, segstart, &nseg_s); break;
    }
}

// ---------------- host ----------------
extern "C" void kernel_launch(void* const* d_in, const int* in_sizes, int n_in,
                              void* d_out, int out_size, void* d_ws, size_t ws_size,
                              hipStream_t stream) {
    const float* x        = (const float*)d_in[0];
    const float* edge_vec = (const float*)d_in[1];
    const float* w1       = (const float*)d_in[2];
    const float* w2       = (const float*)d_in[3];
    const int*   src      = (const int*)d_in[4];
    const int*   dst      = (const int*)d_in[5];
    float* out = (float*)d_out;

    char* ws = (char*)d_ws;
    size_t off = 0;
    auto alloc = [&](size_t n) -> char* {
        off = (off + 255) & ~(size_t)255;
        char* p = ws + off; off += n; return p;
    };
    int* hist    = (int*)alloc(40000);
    int* cursor  = (int*)alloc(40000);
    int* offsets = (int*)alloc(40004);
    int* perm    = (int*)alloc(640000);
    int* dsts    = (int*)alloc(640000);
    char* w2bf   = alloc(131072);
    char* h_bf   = alloc((size_t)NE * 128);
    char* X0g    = alloc((size_t)NE * 32);
    char* Zg     = alloc((size_t)NE * 32);
    char* X1g    = alloc((size_t)NE * 128);
    float* Y1g   = (float*)alloc((size_t)NE * 16);
    const bool big = (off <= ws_size);

    hipMemsetAsync(d_out, 0, (size_t)out_size * sizeof(float), stream);
    hipMemsetAsync(d_ws, 0, 81408, stream);  // hist + cursor

    if (big) {
        hipLaunchKernelGGL(hist_k, dim3(657), dim3(256), 0, stream, dst, hist, w2, w2bf);
        hipLaunchKernelGGL(scan_k, dim3(1), dim3(1024), 0, stream, hist, offsets);
        hipLaunchKernelGGL(prep_k, dim3(1250), dim3(256), 0, stream,
                           x, edge_vec, w1, src, dst, offsets, cursor, dsts,
                           h_bf, X0g, Zg, X1g, Y1g);
        hipLaunchKernelGGL(se3_edge3, dim3(500), dim3(1024), 0, stream,
                           w2bf, h_bf, X0g, Zg, X1g, Y1g, dsts, out);
    } else {
        hipLaunchKernelGGL(hist_k, dim3(625), dim3(256), 0, stream, dst, hist, w2, w2bf);
        hipLaunchKernelGGL(scan_k, dim3(1), dim3(1024), 0, stream, hist, offsets);
        hipLaunchKernelGGL(scatter_k, dim3(625), dim3(256), 0, stream, dst, offsets, cursor, perm, dsts);
        hipLaunchKernelGGL(fb_edge, dim3(1250, 4), dim3(256), 0, stream,
                           x, edge_vec, w1, w2, src, perm, dsts, out);
    }
}